// Round 9
// baseline (24778.789 us; speedup 1.0000x reference)
//
#include <hip/hip_runtime.h>
#include <stdint.h>

#define NB 1024
#define NT 100
#define NPRED 30
#define NE 512
#define NH 1024
#define NG (3*NH)

typedef unsigned short u16;
typedef unsigned int u32;
typedef u16 u16x4 __attribute__((ext_vector_type(4)));
typedef float f32x4 __attribute__((ext_vector_type(4)));
typedef __bf16 bf16x8 __attribute__((ext_vector_type(8)));

__device__ __forceinline__ u16 f2b(float f){
  u32 u = __float_as_uint(f);
  u = (u + 0x7FFFu + ((u >> 16) & 1u)) >> 16;
  return (u16)u;
}
__device__ __forceinline__ float sig_(float x){ return 1.0f/(1.0f+__expf(-x)); }
__device__ __forceinline__ float tanh_(float x){
  float e = __expf(2.0f*fabsf(x));
  return copysignf(1.0f - 2.0f/(e+1.0f), x);
}

// ---------------- fp32 -> bf16 conversion ----------------
__global__ void cvt_kernel(const float* src, u16* dst, int n4){
  int i = blockIdx.x*256 + threadIdx.x;
  if (i < n4){
    f32x4 v = ((const f32x4*)src)[i];
    u16x4 o;
    o[0]=f2b(v[0]); o[1]=f2b(v[1]); o[2]=f2b(v[2]); o[3]=f2b(v[3]);
    ((u16x4*)dst)[i] = o;
  }
}

// ---------------- standalone embedding (loop entry) ----------------
__global__ void emb_kernel(const float* __restrict__ obs, const float* __restrict__ We,
                           const float* __restrict__ be, u16* __restrict__ out, int t){
  int idx = blockIdx.x*256 + threadIdx.x;      // over NB*NE
  int b = idx >> 9, e = idx & 511;
  float x0 = obs[(b*NT + t)*2], x1 = obs[(b*NT + t)*2 + 1];
  out[idx] = f2b(tanh_(We[e*2]*x0 + We[e*2+1]*x1 + be[e]));
}

// ---------------- async global->LDS (16B per lane) ----------------
__device__ __forceinline__ void gload16(const u16* g, const u16* lds){
  __builtin_amdgcn_global_load_lds(
      (const __attribute__((address_space(1))) void*)g,
      (__attribute__((address_space(3))) void*)lds, 16, 0, 0);
}

// ---------------- 128x128 bf16 GEMM tile, BK=64, dbuf LDS, XOR-swizzled ----------------
// (round-5/7 proven body; LDS arrays passed in so the kernel can reuse them.)
__device__ __forceinline__ void gemm_tile_body(
    const u16* __restrict__ A, int lda,
    const u16* __restrict__ W, int K,
    const float* __restrict__ bias, float* __restrict__ C,
    int bRow, int bCol,
    u16 (*As)[128][64], u16 (*Bs)[128][64])
{
  const int tid = threadIdx.x;
  const int w = tid >> 6, l = tid & 63;
  const int wm = w >> 1, wn = w & 1;           // 2x2 waves -> 64x64 per wave
  const int fr = l & 15, lhi = l >> 4;         // fragment row, k-group
  const int srow = l >> 3;
  const int gcol = (((l & 7) ^ srow) * 8);     // pre-swizzled source col (u16)

  f32x4 acc[4][4];
  #pragma unroll
  for (int m=0;m<4;m++)
    #pragma unroll
    for (int n=0;n<4;n++) acc[m][n] = (f32x4)0.0f;

  const u16* Ab = A + (size_t)bRow*lda + gcol;
  const u16* Wb = W + (size_t)bCol*K + gcol;
  const int NK = K >> 6;

  #pragma unroll
  for (int s4=0;s4<4;s4++){
    int slab = w*4 + s4;
    int row = slab*8 + srow;
    gload16(Ab + (size_t)row*lda, &As[0][slab*8][0]);
    gload16(Wb + (size_t)row*K,   &Bs[0][slab*8][0]);
  }
  __syncthreads();

  for (int t = 0; t < NK; ++t){
    const int cur = t & 1;
    if (t + 1 < NK){
      const int k0 = (t+1)*64;
      #pragma unroll
      for (int s4=0;s4<4;s4++){
        int slab = w*4 + s4;
        int row = slab*8 + srow;
        gload16(Ab + (size_t)row*lda + k0, &As[cur^1][slab*8][0]);
        gload16(Wb + (size_t)row*K   + k0, &Bs[cur^1][slab*8][0]);
      }
    }
    const u16* Ac = &As[cur][0][0];
    const u16* Bc = &Bs[cur][0][0];
    #pragma unroll
    for (int kk=0; kk<2; ++kk){
      const int ch = (((kk*4 + lhi) ^ (l & 7)) * 8);   // swizzled 16B chunk
      bf16x8 af[4], bfr[4];
      #pragma unroll
      for (int m=0;m<4;m++)
        af[m] = *(const bf16x8*)(Ac + (size_t)(wm*64 + m*16 + fr)*64 + ch);
      #pragma unroll
      for (int n=0;n<4;n++)
        bfr[n] = *(const bf16x8*)(Bc + (size_t)(wn*64 + n*16 + fr)*64 + ch);
      #pragma unroll
      for (int m=0;m<4;m++)
        #pragma unroll
        for (int n=0;n<4;n++)
          acc[m][n] = __builtin_amdgcn_mfma_f32_16x16x32_bf16(af[m], bfr[n], acc[m][n], 0, 0, 0);
    }
    __syncthreads();
  }

  // epilogue: C/D layout col = lane&15, row = (lane>>4)*4 + reg  [m89/m91 verified]
  const int crow = lhi * 4, ccol = l & 15;
  #pragma unroll
  for (int n=0;n<4;n++){
    int col = bCol + wn*64 + n*16 + ccol;
    float bv = bias[col];
    #pragma unroll
    for (int m=0;m<4;m++){
      int row = bRow + wm*64 + m*16 + crow;
      float* Cp = C + (size_t)row*NG + col;
      #pragma unroll
      for (int r=0;r<4;r++) Cp[(size_t)r*NG] = acc[m][n][r] + bv;
    }
  }
}

// ---------------- dual GEMM + in-kernel fused GRU cell ----------------
// Grid: 384 blocks (XCD-swizzled). z=0 computes gx tile into C0, z=1 gh into C1.
// If counters != nullptr: per 128x128 cell tile (rb,hb) there are 6 producer
// blocks (z in {0,1} x 3 gates). Each producer: threadfence + atomicAdd; the
// 6th finisher computes the GRU cell for that tile (gx/gh are cache-hot),
// writing houtf (fp32, tile-private in-place-safe), houtb (bf16 ping-pong
// plane), optional seq slot, and optionally the NEXT step's embedding slice.
__global__ __launch_bounds__(256)
void gemm_dual_cell_kernel(
  const u16* A0, int lda0, int K0, const u16* W0, const float* bias0, float* C0,
  const u16* A1, int lda1, int K1, const u16* W1, const float* bias1, float* C1,
  u32* __restrict__ counters,
  const float* __restrict__ hin, float* __restrict__ houtf,
  u16* __restrict__ houtb, u16* __restrict__ seq,
  const float* __restrict__ obs, const float* __restrict__ We,
  const float* __restrict__ be, u16* __restrict__ embb, int et)
{
  __shared__ __align__(16) u16 As[2][128][64];
  __shared__ __align__(16) u16 Bs[2][128][64];

  const int id = blockIdx.x;          // 0..383
  const int xcd = id & 7, k = id >> 3;
  const int cb = 3*xcd + (k >> 4);    // 0..23 (gate g = cb>>3, hcol block hb = cb&7)
  const int rem = k & 15;
  const int rb = rem >> 1;            // 0..7
  const int z  = rem & 1;

  if (z == 0)
    gemm_tile_body(A0, lda0, W0, K0, bias0, C0, rb*128, cb*128, As, Bs);
  else
    gemm_tile_body(A1, lda1, W1, K1, bias1, C1, rb*128, cb*128, As, Bs);

  if (!counters) return;

  const int tid = threadIdx.x;
  // last-block pattern: every thread fences its stores, sync, tid0 counts.
  __threadfence();
  __syncthreads();
  volatile u32* flag = (volatile u32*)&As[0][0][0];
  if (tid == 0)
    *flag = atomicAdd(&counters[rb*8 + (cb & 7)], 1u);
  __syncthreads();
  if (*flag != 5) return;
  __threadfence();   // acquire: producers' gate tiles now visible

  const int hb = cb & 7;
  const int row0 = rb * 128;
  const f32x4* gx4 = (const f32x4*)C0;
  const f32x4* gh4 = (const f32x4*)C1;
  const f32x4* hin4 = (const f32x4*)hin;

  for (int it = 0; it < 16; ++it){
    int q = it*256 + tid;             // 0..4095 quads in the 128x128 tile
    int r = q >> 5, cq = q & 31;
    int row = row0 + r;
    size_t gb = (size_t)row*768 + hb*32 + cq;     // NG/4 row stride
    f32x4 xr = gx4[gb], xz = gx4[gb + 256], xn = gx4[gb + 512];
    f32x4 hr = gh4[gb], hz = gh4[gb + 256], hn = gh4[gb + 512];
    size_t hq = (size_t)row*256 + hb*32 + cq;     // NH/4 row stride
    f32x4 hv = hin4[hq];
    f32x4 o; u16x4 ob;
    #pragma unroll
    for (int c=0;c<4;c++){
      float rr = sig_(xr[c] + hr[c]);
      float zz = sig_(xz[c] + hz[c]);
      float nn = tanh_(xn[c] + rr*hn[c]);
      float h = (1.0f - zz)*nn + zz*hv[c];
      o[c] = h; ob[c] = f2b(h);
    }
    ((f32x4*)houtf)[hq] = o;
    ((u16x4*)houtb)[hq] = ob;
    if (seq) ((u16x4*)seq)[hq] = ob;
  }

  // fused next-step embedding: tiles hb<4 cover e in [hb*128, hb*128+128)
  if (embb && hb < 4){
    for (int it = 0; it < 32; ++it){
      int q = it*256 + tid;           // 8192 u32 slots (128 rows x 64 u32)
      int r = q >> 6, cu = q & 63;
      int row = row0 + r;
      float x0 = obs[((size_t)row*NT + et)*2];
      float x1 = obs[((size_t)row*NT + et)*2 + 1];
      int e0 = hb*128 + cu*2;
      u16 v0 = f2b(tanh_(We[e0*2]  *x0 + We[e0*2+1]*x1 + be[e0]));
      u16 v1 = f2b(tanh_(We[e0*2+2]*x0 + We[e0*2+3]*x1 + be[e0+1]));
      ((u32*)embb)[(size_t)row*256 + hb*64 + cu] = (u32)v0 | ((u32)v1 << 16);
    }
  }
}

// ---------------- GRU cell + outproj + decoder embedding (block b = batch row) ----------------
__global__ void gru_cell_out_kernel(const float* __restrict__ gx, const float* __restrict__ gh,
                                    const float* __restrict__ hin, float* __restrict__ hout,
                                    u16* __restrict__ houtb,
                                    const float* __restrict__ Wout, const float* __restrict__ bout,
                                    float* __restrict__ dout, int ot,
                                    const float* __restrict__ Wed, const float* __restrict__ bed,
                                    u16* __restrict__ dembb)
{
  int b = blockIdx.x, tid = threadIdx.x;
  int idx = b*256 + tid;
  int base = b*768;
  const f32x4* gx4 = (const f32x4*)gx;
  const f32x4* gh4 = (const f32x4*)gh;
  f32x4 xr = gx4[base + tid], xz = gx4[base + 256 + tid], xn = gx4[base + 512 + tid];
  f32x4 hr = gh4[base + tid], hz = gh4[base + 256 + tid], hn = gh4[base + 512 + tid];
  f32x4 hv = ((const f32x4*)hin)[idx];
  f32x4 o; u16x4 ob;
  #pragma unroll
  for (int c=0;c<4;c++){
    float r = sig_(xr[c] + hr[c]);
    float z = sig_(xz[c] + hz[c]);
    float n = tanh_(xn[c] + r*hn[c]);
    float h = (1.0f - z)*n + z*hv[c];
    o[c] = h; ob[c] = f2b(h);
  }
  ((f32x4*)hout)[idx] = o;
  ((u16x4*)houtb)[idx] = ob;

  // outproj: s = h[b,:] . Wout
  int j0 = tid*4;
  float s0 = 0.f, s1 = 0.f;
  #pragma unroll
  for (int c=0;c<4;c++){
    s0 += o[c]*Wout[j0+c];
    s1 += o[c]*Wout[NH + j0 + c];
  }
  #pragma unroll
  for (int off = 32; off > 0; off >>= 1){
    s0 += __shfl_down(s0, off);
    s1 += __shfl_down(s1, off);
  }
  __shared__ float red[8];
  __shared__ float lastsh[2];
  int w = tid >> 6;
  if ((tid & 63) == 0){ red[w*2] = s0; red[w*2+1] = s1; }
  __syncthreads();
  if (tid == 0){
    float o0 = red[0]+red[2]+red[4]+red[6] + bout[0];
    float o1 = red[1]+red[3]+red[5]+red[7] + bout[1];
    lastsh[0] = o0; lastsh[1] = o1;
    if (dout){ dout[(size_t)b*(NPRED*2) + ot*2]     = o0;
               dout[(size_t)b*(NPRED*2) + ot*2 + 1] = o1; }
  }
  __syncthreads();
  float x0 = lastsh[0], x1 = lastsh[1];
  int e0 = tid*2;
  u16 v0 = f2b(tanh_(Wed[e0*2]  *x0 + Wed[e0*2+1]*x1 + bed[e0]));
  u16 v1 = f2b(tanh_(Wed[e0*2+2]*x0 + Wed[e0*2+3]*x1 + bed[e0+1]));
  ((u32*)dembb)[b*256 + tid] = (u32)v0 | ((u32)v1 << 16);
}

extern "C" void kernel_launch(void* const* d_in, const int* in_sizes, int n_in,
                              void* d_out, int out_size, void* d_ws, size_t ws_size,
                              hipStream_t stream)
{
  (void)in_sizes; (void)n_in; (void)out_size;
  const float* obs  = (const float*)d_in[0];
  const float* We   = (const float*)d_in[1];
  const float* be   = (const float*)d_in[2];
  const float* Wed  = (const float*)d_in[3];
  const float* bed  = (const float*)d_in[4];
  const float* e1Wih = (const float*)d_in[5];
  const float* e1Whh = (const float*)d_in[6];
  const float* e1bih = (const float*)d_in[7];
  const float* e1bhh = (const float*)d_in[8];
  const float* e2Wih = (const float*)d_in[9];
  const float* e2Whh = (const float*)d_in[10];
  const float* e2bih = (const float*)d_in[11];
  const float* e2bhh = (const float*)d_in[12];
  const float* d1Wih = (const float*)d_in[13];
  const float* d1Whh = (const float*)d_in[14];
  const float* d1bih = (const float*)d_in[15];
  const float* d1bhh = (const float*)d_in[16];
  const float* d2Wih = (const float*)d_in[17];
  const float* d2Whh = (const float*)d_in[18];
  const float* d2bih = (const float*)d_in[19];
  const float* d2bhh = (const float*)d_in[20];
  const float* Wout = (const float*)d_in[21];
  const float* bout = (const float*)d_in[22];
  float* out = (float*)d_out;

  // ---- ws-adaptive workspace layout ----
  char* ws = (char*)d_ws;
  size_t off = 0;
  auto alloc = [&](size_t bytes)->char* {
    char* p = ws + off;
    off += (bytes + 255) & ~(size_t)255;
    return p;
  };
  u16* wE1i = (u16*)alloc((size_t)NG*NE*2);
  u16* wE1h = (u16*)alloc((size_t)NG*NH*2);
  u16* wE2i = (u16*)alloc((size_t)NG*NH*2);
  u16* wE2h = (u16*)alloc((size_t)NG*NH*2);
  u16* wD1i = (u16*)alloc((size_t)NG*NE*2);
  u16* wD1h = (u16*)alloc((size_t)NG*NH*2);
  u16* wD2i = (u16*)alloc((size_t)NG*NH*2);
  u16* wD2h = (u16*)alloc((size_t)NG*NH*2);
  u16* embbP[2] = { (u16*)alloc((size_t)NB*NE*2), (u16*)alloc((size_t)NB*NE*2) };
  u16* dembb = (u16*)alloc((size_t)NB*NE*2);
  float* h1f = (float*)alloc((size_t)NB*NH*4);
  u16*   h1bP[2] = { (u16*)alloc((size_t)NB*NH*2), (u16*)alloc((size_t)NB*NH*2) };
  float* h2f = (float*)alloc((size_t)NB*NH*4);
  u16*   h2bP[2] = { (u16*)alloc((size_t)NB*NH*2), (u16*)alloc((size_t)NB*NH*2) };
  float* gx  = (float*)alloc((size_t)NB*NG*4);
  float* gh  = (float*)alloc((size_t)NB*NG*4);
  u32* counters = (u32*)alloc(336*64*4);

  // enc1 cache: as many TRAILING steps as fit; prefix recomputed in pass 2.
  const size_t slot = (size_t)NB*NH*2;     // 2 MB/step
  size_t avail = (ws_size > off + (1u<<20)) ? (ws_size - off - (1u<<20)) : 0;
  int cs = (int)(avail / slot);
  if (cs > NT) cs = NT;
  u16* cache = (u16*)alloc((size_t)cs * slot);
  const int cache_start = NT - cs;

  // ---- init ----
  hipMemsetAsync(h1f, 0, (size_t)NB*NH*4, stream);
  hipMemsetAsync(h1bP[0], 0, (size_t)NB*NH*2, stream);
  hipMemsetAsync(counters, 0, 336*64*4, stream);
  int cstep = 0;
  auto ctr = [&]()->u32* { return counters + (cstep++)*64; };

  auto cvt = [&](const float* src, u16* dst, size_t n){
    int n4 = (int)(n >> 2);
    cvt_kernel<<<dim3((n4 + 255)/256), dim3(256), 0, stream>>>(src, dst, n4);
  };
  cvt(e1Wih, wE1i, (size_t)NG*NE);
  cvt(e1Whh, wE1h, (size_t)NG*NH);
  cvt(e2Wih, wE2i, (size_t)NG*NH);
  cvt(e2Whh, wE2h, (size_t)NG*NH);
  cvt(d1Wih, wD1i, (size_t)NG*NE);
  cvt(d1Whh, wD1h, (size_t)NG*NH);
  cvt(d2Wih, wD2i, (size_t)NG*NH);
  cvt(d2Whh, wD2h, (size_t)NG*NH);

  const dim3 blk(256);
  const dim3 dual_grid(384);
  const dim3 emb_grid((NB*NE)/256);

  int p1 = 0, p2 = 0, pe = 0;

  // ---- pass 1: GRU1 over all T (fused cell + next-step emb; trailing cache) ----
  emb_kernel<<<emb_grid, blk, 0, stream>>>(obs, We, be, embbP[0], 0);
  for (int t = 0; t < NT; ++t){
    u16* slot_p = (t >= cache_start) ? cache + (size_t)(t - cache_start)*NB*NH : (u16*)nullptr;
    u16* embn = (t + 1 < NT) ? embbP[pe^1] : (u16*)nullptr;
    gemm_dual_cell_kernel<<<dual_grid, blk, 0, stream>>>(
        embbP[pe], NE, NE, wE1i, e1bih, gx,
        h1bP[p1],  NH, NH, wE1h, e1bhh, gh,
        ctr(), h1f, h1f, h1bP[p1^1], slot_p,
        obs, We, be, embn, t+1);
    p1 ^= 1; pe ^= 1;
  }

  // GRU2 initial hidden = GRU1 final hidden (the reference quirk)
  hipMemcpyAsync(h2f, h1f, (size_t)NB*NH*4, hipMemcpyDeviceToDevice, stream);
  hipMemcpyAsync(h2bP[0], h1bP[p1], (size_t)NB*NH*2, hipMemcpyDeviceToDevice, stream);
  p2 = 0;

  // ---- pass 2: GRU2 over all T; recompute GRU1 prefix where not cached ----
  if (cache_start > 0){
    hipMemsetAsync(h1f, 0, (size_t)NB*NH*4, stream);
    hipMemsetAsync(h1bP[0], 0, (size_t)NB*NH*2, stream);
    p1 = 0; pe = 0;
    emb_kernel<<<emb_grid, blk, 0, stream>>>(obs, We, be, embbP[0], 0);
  }
  for (int t = 0; t < cache_start; ++t){
    u16* embn = (t + 1 < cache_start) ? embbP[pe^1] : (u16*)nullptr;
    gemm_dual_cell_kernel<<<dual_grid, blk, 0, stream>>>(
        embbP[pe], NE, NE, wE1i, e1bih, gx,
        h1bP[p1],  NH, NH, wE1h, e1bhh, gh,
        ctr(), h1f, h1f, h1bP[p1^1], (u16*)nullptr,
        obs, We, be, embn, t+1);
    p1 ^= 1; pe ^= 1;
    if (t == NT - 2){
      gemm_dual_cell_kernel<<<dual_grid, blk, 0, stream>>>(
          h1bP[p1], NH, NH, wE2i, e2bih, gx,
          h2bP[p2], NH, NH, wE2h, e2bhh, gh,
          (u32*)nullptr, nullptr, nullptr, nullptr, nullptr,
          nullptr, nullptr, nullptr, nullptr, 0);
      gru_cell_out_kernel<<<dim3(NB), blk, 0, stream>>>(
          gx, gh, h2f, h2f, h2bP[p2^1], Wout, bout, (float*)nullptr, 0, Wed, bed, dembb);
    } else {
      gemm_dual_cell_kernel<<<dual_grid, blk, 0, stream>>>(
          h1bP[p1], NH, NH, wE2i, e2bih, gx,
          h2bP[p2], NH, NH, wE2h, e2bhh, gh,
          ctr(), h2f, h2f, h2bP[p2^1], (u16*)nullptr,
          nullptr, nullptr, nullptr, nullptr, 0);
    }
    p2 ^= 1;
  }
  for (int t = cache_start; t < NT; ++t){
    const u16* enc1_t = cache + (size_t)(t - cache_start)*NB*NH;
    if (t == NT - 2){
      gemm_dual_cell_kernel<<<dual_grid, blk, 0, stream>>>(
          enc1_t,   NH, NH, wE2i, e2bih, gx,
          h2bP[p2], NH, NH, wE2h, e2bhh, gh,
          (u32*)nullptr, nullptr, nullptr, nullptr, nullptr,
          nullptr, nullptr, nullptr, nullptr, 0);
      gru_cell_out_kernel<<<dim3(NB), blk, 0, stream>>>(
          gx, gh, h2f, h2f, h2bP[p2^1], Wout, bout, (float*)nullptr, 0, Wed, bed, dembb);
    } else {
      gemm_dual_cell_kernel<<<dual_grid, blk, 0, stream>>>(
          enc1_t,   NH, NH, wE2i, e2bih, gx,
          h2bP[p2], NH, NH, wE2h, e2bhh, gh,
          ctr(), h2f, h2f, h2bP[p2^1], (u16*)nullptr,
          nullptr, nullptr, nullptr, nullptr, 0);
    }
    p2 ^= 1;
  }

  // ---- autoregressive decoder (carry = h2 plane p2, fixed) ----
  for (int t = 0; t < NPRED; ++t){
    gemm_dual_cell_kernel<<<dual_grid, blk, 0, stream>>>(
        dembb,    NE, NE, wD1i, d1bih, gx,
        h2bP[p2], NH, NH, wD1h, d1bhh, gh,
        ctr(), h2f, h1f, h1bP[0], (u16*)nullptr,
        nullptr, nullptr, nullptr, nullptr, 0);
    gemm_dual_cell_kernel<<<dual_grid, blk, 0, stream>>>(
        h1bP[0], NH, NH, wD2i, d2bih, gx,
        h1bP[0], NH, NH, wD2h, d2bhh, gh,
        (u32*)nullptr, nullptr, nullptr, nullptr, nullptr,
        nullptr, nullptr, nullptr, nullptr, 0);
    gru_cell_out_kernel<<<dim3(NB), blk, 0, stream>>>(
        gx, gh, h1f, h2f, h2bP[p2], Wout, bout, out, t, Wed, bed, dembb);
  }
}

// Round 10
// 12615.928 us; speedup vs baseline: 1.9641x; 1.9641x over previous
//
#include <hip/hip_runtime.h>
#include <stdint.h>

#define NB 1024
#define NT 100
#define NPRED 30
#define NE 512
#define NH 1024
#define NG (3*NH)

typedef unsigned short u16;
typedef unsigned int u32;
typedef u16 u16x4 __attribute__((ext_vector_type(4)));
typedef float f32x4 __attribute__((ext_vector_type(4)));
typedef __bf16 bf16x8 __attribute__((ext_vector_type(8)));

__device__ __forceinline__ u16 f2b(float f){
  u32 u = __float_as_uint(f);
  u = (u + 0x7FFFu + ((u >> 16) & 1u)) >> 16;
  return (u16)u;
}
__device__ __forceinline__ float sig_(float x){ return 1.0f/(1.0f+__expf(-x)); }
__device__ __forceinline__ float tanh_(float x){
  float e = __expf(2.0f*fabsf(x));
  return copysignf(1.0f - 2.0f/(e+1.0f), x);
}

// ---------------- weight packing: gate-interleaved groups of 16 ----------------
// packed row' = (j/16)*48 + g*16 + (j%16)  <->  source row g*NH + j ; bf16 convert.
__global__ void pack_w_kernel(const float* __restrict__ src, u16* __restrict__ dst, int K){
  int idx = blockIdx.x*256 + threadIdx.x;        // over NG*K/4
  int kq = K >> 2;
  int rowp = idx / kq, kc = idx % kq;
  int q = rowp / 48, rem = rowp % 48;
  int g = rem >> 4, s = rem & 15;
  int j = q*16 + s;
  f32x4 v = ((const f32x4*)src)[(size_t)(g*NH + j)*kq + kc];
  u16x4 o;
  o[0]=f2b(v[0]); o[1]=f2b(v[1]); o[2]=f2b(v[2]); o[3]=f2b(v[3]);
  ((u16x4*)dst)[idx] = o;
}

// PB1[row'] = g<2 ? bih+bhh : bhh_n ; PB2[j] = bih_n[j]
__global__ void pack_bias_kernel(const float* __restrict__ bih, const float* __restrict__ bhh,
                                 float* __restrict__ PB1, float* __restrict__ PB2){
  int idx = blockIdx.x*256 + threadIdx.x;        // over NG
  int q = idx / 48, rem = idx % 48;
  int g = rem >> 4, s = rem & 15;
  int j = q*16 + s;
  PB1[idx] = (g < 2) ? (bih[g*NH + j] + bhh[g*NH + j]) : bhh[2*NH + j];
  if (idx < NH) PB2[idx] = bih[2*NH + idx];
}

// ---------------- standalone embedding (loop entry) ----------------
__global__ void emb_kernel(const float* __restrict__ obs, const float* __restrict__ We,
                           const float* __restrict__ be, u16* __restrict__ out, int t){
  int idx = blockIdx.x*256 + threadIdx.x;        // over NB*NE
  int b = idx >> 9, e = idx & 511;
  float x0 = obs[(b*NT + t)*2], x1 = obs[(b*NT + t)*2 + 1];
  out[idx] = f2b(tanh_(We[e*2]*x0 + We[e*2+1]*x1 + be[e]));
}

// ---------------- async global->LDS (16B per lane) ----------------
__device__ __forceinline__ void gload16(const u16* g, const u16* lds){
  __builtin_amdgcn_global_load_lds(
      (const __attribute__((address_space(1))) void*)g,
      (__attribute__((address_space(3))) void*)lds, 16, 0, 0);
}

// ---------------- GEMM phase: 64 x 384 tile, BK=64, dbuf, XOR-swizzled ----------------
// TOX: route n-gate frags (nf%3==2) into accx (gx_n must stay separate).
template<bool TOX>
__device__ __forceinline__ void gemm_phase(
    const u16* __restrict__ A, int lda, int K,
    const u16* __restrict__ W,                 // packed, pre-offset to this block's 384 cols
    int rb, int w, int l,
    f32x4* acc, f32x4* accx,
    u16 (*As)[64][64], u16 (*Ws)[384][64])
{
  const int fr = l & 15, lhi = l >> 4;
  const int srow = l >> 3;
  const int gcol = (((l & 7) ^ srow) * 8);     // pre-swizzled source col (u16)
  const u16* Ab = A + (size_t)(rb*64)*lda + gcol;
  const u16* Wb = W + gcol;
  const int NK = K >> 6;

  #define STAGE_P(buf, kt) do { int _k0 = (kt)*64; \
    _Pragma("unroll") \
    for (int c=0;c<2;c++){ int sl = w*2 + c; \
      gload16(Ab + (size_t)(sl*8+srow)*lda + _k0, &As[(buf)][sl*8][0]); } \
    _Pragma("unroll") \
    for (int c=0;c<12;c++){ int sl = w*12 + c; \
      gload16(Wb + (size_t)(sl*8+srow)*K + _k0, &Ws[(buf)][sl*8][0]); } } while(0)

  STAGE_P(0, 0);
  __syncthreads();

  for (int t = 0; t < NK; ++t){
    const int cur = t & 1;
    if (t + 1 < NK) STAGE_P(cur^1, t+1);
    #pragma unroll
    for (int kk=0; kk<2; ++kk){
      const int ch = (((kk*4 + lhi) ^ (l & 7)) * 8);
      bf16x8 af[4], wf[6];
      #pragma unroll
      for (int m=0;m<4;m++)
        af[m] = *(const bf16x8*)(&As[cur][m*16 + fr][0] + ch);
      #pragma unroll
      for (int nf=0;nf<6;nf++)
        wf[nf] = *(const bf16x8*)(&Ws[cur][w*96 + nf*16 + fr][0] + ch);
      #pragma unroll
      for (int nf=0;nf<6;nf++)
        #pragma unroll
        for (int m=0;m<4;m++){
          if (TOX && (nf % 3) == 2)
            accx[(nf/3)*4 + m] = __builtin_amdgcn_mfma_f32_16x16x32_bf16(af[m], wf[nf], accx[(nf/3)*4 + m], 0, 0, 0);
          else
            acc[nf*4 + m] = __builtin_amdgcn_mfma_f32_16x16x32_bf16(af[m], wf[nf], acc[nf*4 + m], 0, 0, 0);
        }
    }
    __syncthreads();
  }
  #undef STAGE_P
}

// ---------------- fused GRU step: gx-pass + gh-pass + cell epilogue ----------------
// Grid 128 blocks: rb = id>>3 (16 row tiles of 64), cb = id&7 (8 col tiles of 128 h).
__global__ __launch_bounds__(256)
void fused_step(
    const u16* __restrict__ Ax, int ldax, int Kx, const u16* __restrict__ Wx,
    const u16* __restrict__ Ah, const u16* __restrict__ Wh,
    const float* __restrict__ PB1, const float* __restrict__ PB2,
    const float* __restrict__ hin, float* __restrict__ houtf,
    u16* __restrict__ houtb, u16* __restrict__ seq,
    const float* __restrict__ obs, const float* __restrict__ We,
    const float* __restrict__ be, u16* __restrict__ embb, int et)
{
  __shared__ __align__(16) u16 As[2][64][64];
  __shared__ __align__(16) u16 Ws[2][384][64];

  const int rb = blockIdx.x >> 3, cb = blockIdx.x & 7;
  const int tid = threadIdx.x, w = tid >> 6, l = tid & 63;
  const int s = l & 15, lhi = l >> 4;

  f32x4 acc[24], accx[8];
  #pragma unroll
  for (int i=0;i<24;i++) acc[i] = (f32x4)0.0f;
  #pragma unroll
  for (int i=0;i<8;i++) accx[i] = (f32x4)0.0f;

  gemm_phase<true >(Ax, ldax, Kx, Wx + (size_t)(cb*384)*Kx, rb, w, l, acc, accx, As, Ws);
  gemm_phase<false>(Ah, NH,   NH, Wh + (size_t)(cb*384)*NH, rb, w, l, acc, accx, As, Ws);

  // ---- cell epilogue: this block owns rows [rb*64, +64) x h-cols [cb*128, +128) ----
  #pragma unroll
  for (int gi=0; gi<2; ++gi){
    int j = cb*128 + (2*w + gi)*16 + s;
    int pbase = cb*384 + w*96 + gi*48 + s;
    float pbr = PB1[pbase], pbz = PB1[pbase + 16], pbn = PB1[pbase + 32];
    float pb2 = PB2[j];
    #pragma unroll
    for (int m=0;m<4;m++){
      #pragma unroll
      for (int r=0;r<4;r++){
        int row = rb*64 + m*16 + lhi*4 + r;
        size_t hoff = (size_t)row*NH + j;
        float rpre = acc[(gi*3+0)*4 + m][r] + pbr;
        float zpre = acc[(gi*3+1)*4 + m][r] + pbz;
        float nh   = acc[(gi*3+2)*4 + m][r] + pbn;
        float nx   = accx[gi*4 + m][r] + pb2;
        float r_ = sig_(rpre), z_ = sig_(zpre);
        float nn = tanh_(nx + r_*nh);
        float h = (1.0f - z_)*nn + z_*hin[hoff];
        houtf[hoff] = h;
        u16 hb = f2b(h);
        houtb[hoff] = hb;
        if (seq) seq[hoff] = hb;
      }
    }
  }

  // ---- fused next-step embedding: rows [rb*64,+64) x emb cols [cb*64,+64) ----
  if (embb){
    int row = rb*64 + (tid >> 2);
    float x0 = obs[((size_t)row*NT + et)*2];
    float x1 = obs[((size_t)row*NT + et)*2 + 1];
    #pragma unroll
    for (int c=0;c<8;c++){
      int e = cb*64 + ((tid & 3)*8 + c)*2;
      u16 v0 = f2b(tanh_(We[e*2]  *x0 + We[e*2+1]*x1 + be[e]));
      u16 v1 = f2b(tanh_(We[e*2+2]*x0 + We[e*2+3]*x1 + be[e+1]));
      ((u32*)embb)[(size_t)row*256 + cb*32 + (tid & 3)*8 + c] = (u32)v0 | ((u32)v1 << 16);
    }
  }
}

// ---------------- output projection + decoder embedding (block = batch row) ----------------
__global__ void outproj_demb_kernel(const float* __restrict__ h,
                                    const float* __restrict__ Wout, const float* __restrict__ bout,
                                    float* __restrict__ dout, int ot,
                                    const float* __restrict__ Wed, const float* __restrict__ bed,
                                    u16* __restrict__ dembb)
{
  int b = blockIdx.x, tid = threadIdx.x;
  f32x4 hv = ((const f32x4*)h)[b*256 + tid];
  int j0 = tid*4;
  float s0 = 0.f, s1 = 0.f;
  #pragma unroll
  for (int c=0;c<4;c++){
    s0 += hv[c]*Wout[j0+c];
    s1 += hv[c]*Wout[NH + j0 + c];
  }
  #pragma unroll
  for (int off = 32; off > 0; off >>= 1){
    s0 += __shfl_down(s0, off);
    s1 += __shfl_down(s1, off);
  }
  __shared__ float red[8];
  __shared__ float lastsh[2];
  int w = tid >> 6;
  if ((tid & 63) == 0){ red[w*2] = s0; red[w*2+1] = s1; }
  __syncthreads();
  if (tid == 0){
    float o0 = red[0]+red[2]+red[4]+red[6] + bout[0];
    float o1 = red[1]+red[3]+red[5]+red[7] + bout[1];
    lastsh[0] = o0; lastsh[1] = o1;
    if (dout){ dout[(size_t)b*(NPRED*2) + ot*2]     = o0;
               dout[(size_t)b*(NPRED*2) + ot*2 + 1] = o1; }
  }
  __syncthreads();
  float x0 = lastsh[0], x1 = lastsh[1];
  int e0 = tid*2;
  u16 v0 = f2b(tanh_(Wed[e0*2]  *x0 + Wed[e0*2+1]*x1 + bed[e0]));
  u16 v1 = f2b(tanh_(Wed[e0*2+2]*x0 + Wed[e0*2+3]*x1 + bed[e0+1]));
  ((u32*)dembb)[b*256 + tid] = (u32)v0 | ((u32)v1 << 16);
}

extern "C" void kernel_launch(void* const* d_in, const int* in_sizes, int n_in,
                              void* d_out, int out_size, void* d_ws, size_t ws_size,
                              hipStream_t stream)
{
  (void)in_sizes; (void)n_in; (void)out_size;
  const float* obs  = (const float*)d_in[0];
  const float* We   = (const float*)d_in[1];
  const float* be   = (const float*)d_in[2];
  const float* Wed  = (const float*)d_in[3];
  const float* bed  = (const float*)d_in[4];
  const float* e1Wih = (const float*)d_in[5];
  const float* e1Whh = (const float*)d_in[6];
  const float* e1bih = (const float*)d_in[7];
  const float* e1bhh = (const float*)d_in[8];
  const float* e2Wih = (const float*)d_in[9];
  const float* e2Whh = (const float*)d_in[10];
  const float* e2bih = (const float*)d_in[11];
  const float* e2bhh = (const float*)d_in[12];
  const float* d1Wih = (const float*)d_in[13];
  const float* d1Whh = (const float*)d_in[14];
  const float* d1bih = (const float*)d_in[15];
  const float* d1bhh = (const float*)d_in[16];
  const float* d2Wih = (const float*)d_in[17];
  const float* d2Whh = (const float*)d_in[18];
  const float* d2bih = (const float*)d_in[19];
  const float* d2bhh = (const float*)d_in[20];
  const float* Wout = (const float*)d_in[21];
  const float* bout = (const float*)d_in[22];
  float* out = (float*)d_out;

  // ---- workspace ----
  char* ws = (char*)d_ws;
  size_t off = 0;
  auto alloc = [&](size_t bytes)->char* {
    char* p = ws + off;
    off += (bytes + 255) & ~(size_t)255;
    return p;
  };
  u16* pE1i = (u16*)alloc((size_t)NG*NE*2);
  u16* pE1h = (u16*)alloc((size_t)NG*NH*2);
  u16* pE2i = (u16*)alloc((size_t)NG*NH*2);
  u16* pE2h = (u16*)alloc((size_t)NG*NH*2);
  u16* pD1i = (u16*)alloc((size_t)NG*NE*2);
  u16* pD1h = (u16*)alloc((size_t)NG*NH*2);
  u16* pD2i = (u16*)alloc((size_t)NG*NH*2);
  u16* pD2h = (u16*)alloc((size_t)NG*NH*2);
  float* PB1e1 = (float*)alloc(NG*4); float* PB2e1 = (float*)alloc(NH*4);
  float* PB1e2 = (float*)alloc(NG*4); float* PB2e2 = (float*)alloc(NH*4);
  float* PB1d1 = (float*)alloc(NG*4); float* PB2d1 = (float*)alloc(NH*4);
  float* PB1d2 = (float*)alloc(NG*4); float* PB2d2 = (float*)alloc(NH*4);
  u16* embbP[2] = { (u16*)alloc((size_t)NB*NE*2), (u16*)alloc((size_t)NB*NE*2) };
  u16* dembb = (u16*)alloc((size_t)NB*NE*2);
  float* h1f = (float*)alloc((size_t)NB*NH*4);
  u16*   h1bP[2] = { (u16*)alloc((size_t)NB*NH*2), (u16*)alloc((size_t)NB*NH*2) };
  float* h2f = (float*)alloc((size_t)NB*NH*4);
  u16*   h2bP[2] = { (u16*)alloc((size_t)NB*NH*2), (u16*)alloc((size_t)NB*NH*2) };

  // enc1 cache: as many TRAILING steps as fit; prefix recomputed in pass 2.
  const size_t slot = (size_t)NB*NH*2;     // 2 MB/step
  size_t avail = (ws_size > off + (1u<<20)) ? (ws_size - off - (1u<<20)) : 0;
  int cs = (int)(avail / slot);
  if (cs > NT) cs = NT;
  u16* cache = (u16*)alloc((size_t)cs * slot);
  const int cache_start = NT - cs;

  // ---- init + packing ----
  hipMemsetAsync(h1f, 0, (size_t)NB*NH*4, stream);
  hipMemsetAsync(h1bP[0], 0, (size_t)NB*NH*2, stream);

  const dim3 blk(256);
  auto packw = [&](const float* src, u16* dst, int K){
    pack_w_kernel<<<dim3((NG*K/4)/256), blk, 0, stream>>>(src, dst, K);
  };
  packw(e1Wih, pE1i, NE); packw(e1Whh, pE1h, NH);
  packw(e2Wih, pE2i, NH); packw(e2Whh, pE2h, NH);
  packw(d1Wih, pD1i, NE); packw(d1Whh, pD1h, NH);
  packw(d2Wih, pD2i, NH); packw(d2Whh, pD2h, NH);
  pack_bias_kernel<<<dim3(NG/256), blk, 0, stream>>>(e1bih, e1bhh, PB1e1, PB2e1);
  pack_bias_kernel<<<dim3(NG/256), blk, 0, stream>>>(e2bih, e2bhh, PB1e2, PB2e2);
  pack_bias_kernel<<<dim3(NG/256), blk, 0, stream>>>(d1bih, d1bhh, PB1d1, PB2d1);
  pack_bias_kernel<<<dim3(NG/256), blk, 0, stream>>>(d2bih, d2bhh, PB1d2, PB2d2);

  const dim3 fgrid(128);
  const dim3 emb_grid((NB*NE)/256);

  int p1 = 0, p2 = 0, pe = 0;

  // ---- pass 1: GRU1 (one fused launch per step; trailing cache; next-emb fused) ----
  emb_kernel<<<emb_grid, blk, 0, stream>>>(obs, We, be, embbP[0], 0);
  for (int t = 0; t < NT; ++t){
    u16* slot_p = (t >= cache_start) ? cache + (size_t)(t - cache_start)*NB*NH : (u16*)nullptr;
    u16* embn = (t + 1 < NT) ? embbP[pe^1] : (u16*)nullptr;
    fused_step<<<fgrid, blk, 0, stream>>>(
        embbP[pe], NE, NE, pE1i, h1bP[p1], pE1h, PB1e1, PB2e1,
        h1f, h1f, h1bP[p1^1], slot_p,
        obs, We, be, embn, t+1);
    p1 ^= 1; pe ^= 1;
  }

  // GRU2 initial hidden = GRU1 final hidden (the reference quirk)
  hipMemcpyAsync(h2f, h1f, (size_t)NB*NH*4, hipMemcpyDeviceToDevice, stream);
  hipMemcpyAsync(h2bP[0], h1bP[p1], (size_t)NB*NH*2, hipMemcpyDeviceToDevice, stream);
  p2 = 0;

  // ---- pass 2: GRU2; recompute GRU1 prefix where not cached ----
  if (cache_start > 0){
    hipMemsetAsync(h1f, 0, (size_t)NB*NH*4, stream);
    hipMemsetAsync(h1bP[0], 0, (size_t)NB*NH*2, stream);
    p1 = 0; pe = 0;
    emb_kernel<<<emb_grid, blk, 0, stream>>>(obs, We, be, embbP[0], 0);
  }
  for (int t = 0; t < cache_start; ++t){
    u16* embn = (t + 1 < cache_start) ? embbP[pe^1] : (u16*)nullptr;
    fused_step<<<fgrid, blk, 0, stream>>>(
        embbP[pe], NE, NE, pE1i, h1bP[p1], pE1h, PB1e1, PB2e1,
        h1f, h1f, h1bP[p1^1], (u16*)nullptr,
        obs, We, be, embn, t+1);
    p1 ^= 1; pe ^= 1;
    fused_step<<<fgrid, blk, 0, stream>>>(
        h1bP[p1], NH, NH, pE2i, h2bP[p2], pE2h, PB1e2, PB2e2,
        h2f, h2f, h2bP[p2^1], (u16*)nullptr,
        nullptr, nullptr, nullptr, nullptr, 0);
    p2 ^= 1;
    if (t == NT - 2)
      outproj_demb_kernel<<<dim3(NB), blk, 0, stream>>>(
          h2f, Wout, bout, (float*)nullptr, 0, Wed, bed, dembb);
  }
  for (int t = cache_start; t < NT; ++t){
    const u16* enc1_t = cache + (size_t)(t - cache_start)*NB*NH;
    fused_step<<<fgrid, blk, 0, stream>>>(
        enc1_t, NH, NH, pE2i, h2bP[p2], pE2h, PB1e2, PB2e2,
        h2f, h2f, h2bP[p2^1], (u16*)nullptr,
        nullptr, nullptr, nullptr, nullptr, 0);
    p2 ^= 1;
    if (t == NT - 2)
      outproj_demb_kernel<<<dim3(NB), blk, 0, stream>>>(
          h2f, Wout, bout, (float*)nullptr, 0, Wed, bed, dembb);
  }

  // ---- autoregressive decoder ----
  for (int t = 0; t < NPRED; ++t){
    fused_step<<<fgrid, blk, 0, stream>>>(
        dembb, NE, NE, pD1i, h2bP[p2], pD1h, PB1d1, PB2d1,
        h2f, h1f, h1bP[0], (u16*)nullptr,
        nullptr, nullptr, nullptr, nullptr, 0);
    fused_step<<<fgrid, blk, 0, stream>>>(
        h1bP[0], NH, NH, pD2i, h1bP[0], pD2h, PB1d2, PB2d2,
        h1f, h2f, h2bP[p2^1], (u16*)nullptr,
        nullptr, nullptr, nullptr, nullptr, 0);
    p2 ^= 1;
    outproj_demb_kernel<<<dim3(NB), blk, 0, stream>>>(
        h2f, Wout, bout, out, t, Wed, bed, dembb);
  }
}

// Round 11
// 8549.296 us; speedup vs baseline: 2.8983x; 1.4757x over previous
//
#include <hip/hip_runtime.h>
#include <stdint.h>

#define NB 1024
#define NT 100
#define NPRED 30
#define NE 512
#define NH 1024
#define NG (3*NH)

typedef unsigned short u16;
typedef unsigned int u32;
typedef u16 u16x4 __attribute__((ext_vector_type(4)));
typedef float f32x4 __attribute__((ext_vector_type(4)));
typedef __bf16 bf16x8 __attribute__((ext_vector_type(8)));

__device__ __forceinline__ u16 f2b(float f){
  u32 u = __float_as_uint(f);
  u = (u + 0x7FFFu + ((u >> 16) & 1u)) >> 16;
  return (u16)u;
}
__device__ __forceinline__ float sig_(float x){ return 1.0f/(1.0f+__expf(-x)); }
__device__ __forceinline__ float tanh_(float x){
  float e = __expf(2.0f*fabsf(x));
  return copysignf(1.0f - 2.0f/(e+1.0f), x);
}

// ---------------- fp32 -> bf16 conversion ----------------
__global__ void cvt_kernel(const float* src, u16* dst, int n4){
  int i = blockIdx.x*256 + threadIdx.x;
  if (i < n4){
    f32x4 v = ((const f32x4*)src)[i];
    u16x4 o;
    o[0]=f2b(v[0]); o[1]=f2b(v[1]); o[2]=f2b(v[2]); o[3]=f2b(v[3]);
    ((u16x4*)dst)[i] = o;
  }
}

// ---------------- standalone first-step embedding ----------------
__global__ void emb_kernel(const float* __restrict__ obs, const float* __restrict__ We,
                           const float* __restrict__ be, u16* __restrict__ out, int t){
  int idx = blockIdx.x*256 + threadIdx.x;      // over NB*NE
  int b = idx >> 9, e = idx & 511;
  float x0 = obs[(b*NT + t)*2], x1 = obs[(b*NT + t)*2 + 1];
  out[idx] = f2b(tanh_(We[e*2]*x0 + We[e*2+1]*x1 + be[e]));
}

// ---------------- async global->LDS (16B per lane) ----------------
__device__ __forceinline__ void gload16(const u16* g, const u16* lds){
  __builtin_amdgcn_global_load_lds(
      (const __attribute__((address_space(1))) void*)g,
      (__attribute__((address_space(3))) void*)lds, 16, 0, 0);
}

// ---------------- 128x128 bf16 GEMM tile, BK=64, dbuf LDS, XOR-swizzled ----------------
// (round-5/7/8 proven body). LDS(row, chunk16B) holds global(row, chunk ^ (row&7)).
__device__ __forceinline__ void gemm_tile_body(
    const u16* __restrict__ A, int lda,
    const u16* __restrict__ W, int K,
    const float* __restrict__ bias, float* __restrict__ C,
    int bRow, int bCol)
{
  __shared__ __align__(16) u16 As[2][128][64];
  __shared__ __align__(16) u16 Bs[2][128][64];

  const int tid = threadIdx.x;
  const int w = tid >> 6, l = tid & 63;
  const int wm = w >> 1, wn = w & 1;           // 2x2 waves -> 64x64 per wave
  const int fr = l & 15, lhi = l >> 4;         // fragment row, k-group
  const int srow = l >> 3;
  const int gcol = (((l & 7) ^ srow) * 8);     // pre-swizzled source col (u16)

  f32x4 acc[4][4];
  #pragma unroll
  for (int m=0;m<4;m++)
    #pragma unroll
    for (int n=0;n<4;n++) acc[m][n] = (f32x4)0.0f;

  const u16* Ab = A + (size_t)bRow*lda + gcol;
  const u16* Wb = W + (size_t)bCol*K + gcol;
  const int NK = K >> 6;

  #pragma unroll
  for (int s4=0;s4<4;s4++){
    int slab = w*4 + s4;
    int row = slab*8 + srow;
    gload16(Ab + (size_t)row*lda, &As[0][slab*8][0]);
    gload16(Wb + (size_t)row*K,   &Bs[0][slab*8][0]);
  }
  __syncthreads();

  for (int t = 0; t < NK; ++t){
    const int cur = t & 1;
    if (t + 1 < NK){
      const int k0 = (t+1)*64;
      #pragma unroll
      for (int s4=0;s4<4;s4++){
        int slab = w*4 + s4;
        int row = slab*8 + srow;
        gload16(Ab + (size_t)row*lda + k0, &As[cur^1][slab*8][0]);
        gload16(Wb + (size_t)row*K   + k0, &Bs[cur^1][slab*8][0]);
      }
    }
    const u16* Ac = &As[cur][0][0];
    const u16* Bc = &Bs[cur][0][0];
    #pragma unroll
    for (int kk=0; kk<2; ++kk){
      const int ch = (((kk*4 + lhi) ^ (l & 7)) * 8);   // swizzled 16B chunk
      bf16x8 af[4], bfr[4];
      #pragma unroll
      for (int m=0;m<4;m++)
        af[m] = *(const bf16x8*)(Ac + (size_t)(wm*64 + m*16 + fr)*64 + ch);
      #pragma unroll
      for (int n=0;n<4;n++)
        bfr[n] = *(const bf16x8*)(Bc + (size_t)(wn*64 + n*16 + fr)*64 + ch);
      #pragma unroll
      for (int m=0;m<4;m++)
        #pragma unroll
        for (int n=0;n<4;n++)
          acc[m][n] = __builtin_amdgcn_mfma_f32_16x16x32_bf16(af[m], bfr[n], acc[m][n], 0, 0, 0);
    }
    __syncthreads();
  }

  // epilogue: C/D layout col = lane&15, row = (lane>>4)*4 + reg  [m89/m91 verified]
  const int crow = lhi * 4, ccol = l & 15;
  #pragma unroll
  for (int n=0;n<4;n++){
    int col = bCol + wn*64 + n*16 + ccol;
    float bv = bias[col];
    #pragma unroll
    for (int m=0;m<4;m++){
      int row = bRow + wm*64 + m*16 + crow;
      float* Cp = C + (size_t)row*NG + col;
      #pragma unroll
      for (int r=0;r<4;r++)
        __builtin_nontemporal_store(acc[m][n][r] + bv, Cp + (size_t)r*NG);
    }
  }
}

// dual GEMM, flattened 1D grid of 384 with bijective XCD-aware swizzle
__global__ __launch_bounds__(256)
void gemm_dual_kernel(
  const u16* A0, int lda0, int K0, const u16* W0, const float* bias0, float* C0,
  const u16* A1, int lda1, int K1, const u16* W1, const float* bias1, float* C1)
{
  const int id = blockIdx.x;          // 0..383
  const int xcd = id & 7, k = id >> 3;
  const int cb = 3*xcd + (k >> 4);    // 0..23
  const int rem = k & 15;
  const int rb = rem >> 1;            // 0..7
  const int z  = rem & 1;

  if (z == 0)
    gemm_tile_body(A0, lda0, W0, K0, bias0, C0, rb*128, cb*128);
  else
    gemm_tile_body(A1, lda1, W1, K1, bias1, C1, rb*128, cb*128);
}

// ---------------- GRU cell core (block b = batch row b, 256 thr) ----------------
// Gates are read exactly once -> nontemporal loads (no L2 pollution).
__device__ __forceinline__ void cell_core(
    const float* __restrict__ gx, const float* __restrict__ gh,
    const float* __restrict__ hin, float* __restrict__ hout,
    u16* __restrict__ houtb, u16* __restrict__ seq,
    int b, int jq, f32x4& o)
{
  int idx = b*256 + jq;
  int base = b*768;
  const f32x4* gx4 = (const f32x4*)gx;
  const f32x4* gh4 = (const f32x4*)gh;
  f32x4 xr = __builtin_nontemporal_load(gx4 + base + jq);
  f32x4 xz = __builtin_nontemporal_load(gx4 + base + 256 + jq);
  f32x4 xn = __builtin_nontemporal_load(gx4 + base + 512 + jq);
  f32x4 hr = __builtin_nontemporal_load(gh4 + base + jq);
  f32x4 hz = __builtin_nontemporal_load(gh4 + base + 256 + jq);
  f32x4 hn = __builtin_nontemporal_load(gh4 + base + 512 + jq);
  f32x4 hv = ((const f32x4*)hin)[idx];
  u16x4 ob;
  #pragma unroll
  for (int c=0;c<4;c++){
    float r = sig_(xr[c] + hr[c]);
    float z = sig_(xz[c] + hz[c]);
    float n = tanh_(xn[c] + r*hn[c]);
    float h = (1.0f - z)*n + z*hv[c];
    o[c] = h; ob[c] = f2b(h);
  }
  ((f32x4*)hout)[idx] = o;
  ((u16x4*)houtb)[idx] = ob;
  if (seq) __builtin_nontemporal_store(ob, (u16x4*)seq + idx);
}

// plain cell
__global__ void gru_cell_kernel(const float* __restrict__ gx, const float* __restrict__ gh,
                                const float* __restrict__ hin, float* __restrict__ hout,
                                u16* __restrict__ houtb, u16* __restrict__ seq)
{
  f32x4 o;
  cell_core(gx, gh, hin, hout, houtb, seq, blockIdx.x, threadIdx.x, o);
}

// cell + fused next-step input embedding (encoder)
__global__ void gru_cell_emb_kernel(const float* __restrict__ gx, const float* __restrict__ gh,
                                    const float* __restrict__ hin, float* __restrict__ hout,
                                    u16* __restrict__ houtb, u16* __restrict__ seq,
                                    const float* __restrict__ obs, const float* __restrict__ We,
                                    const float* __restrict__ be, u16* __restrict__ embb, int et)
{
  int b = blockIdx.x, tid = threadIdx.x;
  f32x4 o;
  cell_core(gx, gh, hin, hout, houtb, seq, b, tid, o);
  if (embb){
    float x0 = obs[(b*NT + et)*2], x1 = obs[(b*NT + et)*2 + 1];
    int e0 = tid*2;
    u16 v0 = f2b(tanh_(We[e0*2]  *x0 + We[e0*2+1]*x1 + be[e0]));
    u16 v1 = f2b(tanh_(We[e0*2+2]*x0 + We[e0*2+3]*x1 + be[e0+1]));
    ((u32*)embb)[b*256 + tid] = (u32)v0 | ((u32)v1 << 16);
  }
}

// cell + fused output projection + fused decoder embedding
__global__ void gru_cell_out_kernel(const float* __restrict__ gx, const float* __restrict__ gh,
                                    const float* __restrict__ hin, float* __restrict__ hout,
                                    u16* __restrict__ houtb,
                                    const float* __restrict__ Wout, const float* __restrict__ bout,
                                    float* __restrict__ dout, int ot,
                                    const float* __restrict__ Wed, const float* __restrict__ bed,
                                    u16* __restrict__ dembb)
{
  int b = blockIdx.x, tid = threadIdx.x;
  f32x4 o;
  cell_core(gx, gh, hin, hout, houtb, (u16*)nullptr, b, tid, o);

  // outproj: s = h[b,:] . Wout  (block-local reduction)
  int j0 = tid*4;
  float s0 = 0.f, s1 = 0.f;
  #pragma unroll
  for (int c=0;c<4;c++){
    s0 += o[c]*Wout[j0+c];
    s1 += o[c]*Wout[NH + j0 + c];
  }
  #pragma unroll
  for (int off = 32; off > 0; off >>= 1){
    s0 += __shfl_down(s0, off);
    s1 += __shfl_down(s1, off);
  }
  __shared__ float red[8];
  __shared__ float lastsh[2];
  int w = tid >> 6;
  if ((tid & 63) == 0){ red[w*2] = s0; red[w*2+1] = s1; }
  __syncthreads();
  if (tid == 0){
    float o0 = red[0]+red[2]+red[4]+red[6] + bout[0];
    float o1 = red[1]+red[3]+red[5]+red[7] + bout[1];
    lastsh[0] = o0; lastsh[1] = o1;
    if (dout){ dout[(size_t)b*(NPRED*2) + ot*2]     = o0;
               dout[(size_t)b*(NPRED*2) + ot*2 + 1] = o1; }
  }
  __syncthreads();
  // demb: dembb[b, e] = tanh(Wed[e,:] . last + bed[e])
  float x0 = lastsh[0], x1 = lastsh[1];
  int e0 = tid*2;
  u16 v0 = f2b(tanh_(Wed[e0*2]  *x0 + Wed[e0*2+1]*x1 + bed[e0]));
  u16 v1 = f2b(tanh_(Wed[e0*2+2]*x0 + Wed[e0*2+3]*x1 + bed[e0+1]));
  ((u32*)dembb)[b*256 + tid] = (u32)v0 | ((u32)v1 << 16);
}

extern "C" void kernel_launch(void* const* d_in, const int* in_sizes, int n_in,
                              void* d_out, int out_size, void* d_ws, size_t ws_size,
                              hipStream_t stream)
{
  (void)in_sizes; (void)n_in; (void)out_size;
  const float* obs  = (const float*)d_in[0];
  const float* We   = (const float*)d_in[1];
  const float* be   = (const float*)d_in[2];
  const float* Wed  = (const float*)d_in[3];
  const float* bed  = (const float*)d_in[4];
  const float* e1Wih = (const float*)d_in[5];
  const float* e1Whh = (const float*)d_in[6];
  const float* e1bih = (const float*)d_in[7];
  const float* e1bhh = (const float*)d_in[8];
  const float* e2Wih = (const float*)d_in[9];
  const float* e2Whh = (const float*)d_in[10];
  const float* e2bih = (const float*)d_in[11];
  const float* e2bhh = (const float*)d_in[12];
  const float* d1Wih = (const float*)d_in[13];
  const float* d1Whh = (const float*)d_in[14];
  const float* d1bih = (const float*)d_in[15];
  const float* d1bhh = (const float*)d_in[16];
  const float* d2Wih = (const float*)d_in[17];
  const float* d2Whh = (const float*)d_in[18];
  const float* d2bih = (const float*)d_in[19];
  const float* d2bhh = (const float*)d_in[20];
  const float* Wout = (const float*)d_in[21];
  const float* bout = (const float*)d_in[22];
  float* out = (float*)d_out;

  // ---- ws-adaptive workspace layout ----
  char* ws = (char*)d_ws;
  size_t off = 0;
  auto alloc = [&](size_t bytes)->char* {
    char* p = ws + off;
    off += (bytes + 255) & ~(size_t)255;
    return p;
  };
  u16* wE1i = (u16*)alloc((size_t)NG*NE*2);
  u16* wE1h = (u16*)alloc((size_t)NG*NH*2);
  u16* wE2i = (u16*)alloc((size_t)NG*NH*2);
  u16* wE2h = (u16*)alloc((size_t)NG*NH*2);
  u16* wD1i = (u16*)alloc((size_t)NG*NE*2);
  u16* wD1h = (u16*)alloc((size_t)NG*NH*2);
  u16* wD2i = (u16*)alloc((size_t)NG*NH*2);
  u16* wD2h = (u16*)alloc((size_t)NG*NH*2);
  u16* embb  = (u16*)alloc((size_t)NB*NE*2);
  u16* dembb = (u16*)alloc((size_t)NB*NE*2);
  float* h1f = (float*)alloc((size_t)NB*NH*4);
  u16*   h1b = (u16*)alloc((size_t)NB*NH*2);
  float* h2f = (float*)alloc((size_t)NB*NH*4);
  u16*   h2b = (u16*)alloc((size_t)NB*NH*2);
  float* gx  = (float*)alloc((size_t)NB*NG*4);
  float* gh  = (float*)alloc((size_t)NB*NG*4);

  // enc1 cache: as many TRAILING steps as fit; prefix recomputed in pass 2.
  const size_t slot = (size_t)NB*NH*2;     // 2 MB/step
  size_t avail = (ws_size > off + (1u<<20)) ? (ws_size - off - (1u<<20)) : 0;
  int cs = (int)(avail / slot);
  if (cs > NT) cs = NT;
  u16* cache = (u16*)alloc((size_t)cs * slot);
  const int cache_start = NT - cs;

  // ---- init ----
  hipMemsetAsync(h1f, 0, (size_t)NB*NH*4, stream);
  hipMemsetAsync(h1b, 0, (size_t)NB*NH*2, stream);

  auto cvt = [&](const float* src, u16* dst, size_t n){
    int n4 = (int)(n >> 2);
    cvt_kernel<<<dim3((n4 + 255)/256), dim3(256), 0, stream>>>(src, dst, n4);
  };
  cvt(e1Wih, wE1i, (size_t)NG*NE);
  cvt(e1Whh, wE1h, (size_t)NG*NH);
  cvt(e2Wih, wE2i, (size_t)NG*NH);
  cvt(e2Whh, wE2h, (size_t)NG*NH);
  cvt(d1Wih, wD1i, (size_t)NG*NE);
  cvt(d1Whh, wD1h, (size_t)NG*NH);
  cvt(d2Wih, wD2i, (size_t)NG*NH);
  cvt(d2Whh, wD2h, (size_t)NG*NH);

  const dim3 blk(256);
  const dim3 dual_grid(384);                 // flattened, XCD-swizzled
  const dim3 emb_grid((NB*NE)/256);          // 2048
  const dim3 cell_grid(NB);                  // block = batch row

  // ---- pass 1: GRU1 over all T (stores trailing cs outputs; emb fused) ----
  emb_kernel<<<emb_grid, blk, 0, stream>>>(obs, We, be, embb, 0);
  for (int t = 0; t < NT; ++t){
    gemm_dual_kernel<<<dual_grid, blk, 0, stream>>>(
        embb, NE, NE, wE1i, e1bih, gx,
        h1b,  NH, NH, wE1h, e1bhh, gh);
    u16* slot_p = (t >= cache_start) ? cache + (size_t)(t - cache_start)*NB*NH : (u16*)nullptr;
    gru_cell_emb_kernel<<<cell_grid, blk, 0, stream>>>(
        gx, gh, h1f, h1f, h1b, slot_p,
        obs, We, be, (t+1 < NT) ? embb : (u16*)nullptr, t+1);
  }

  // GRU2 initial hidden = GRU1 final hidden (the reference quirk)
  hipMemcpyAsync(h2f, h1f, (size_t)NB*NH*4, hipMemcpyDeviceToDevice, stream);
  hipMemcpyAsync(h2b, h1b, (size_t)NB*NH*2, hipMemcpyDeviceToDevice, stream);

  // ---- pass 2: GRU2 over all T; recompute GRU1 prefix where not cached ----
  if (cache_start > 0){
    hipMemsetAsync(h1f, 0, (size_t)NB*NH*4, stream);
    hipMemsetAsync(h1b, 0, (size_t)NB*NH*2, stream);
    emb_kernel<<<emb_grid, blk, 0, stream>>>(obs, We, be, embb, 0);
  }
  for (int t = 0; t < cache_start; ++t){
    gemm_dual_kernel<<<dual_grid, blk, 0, stream>>>(
        embb, NE, NE, wE1i, e1bih, gx,
        h1b,  NH, NH, wE1h, e1bhh, gh);
    gru_cell_emb_kernel<<<cell_grid, blk, 0, stream>>>(
        gx, gh, h1f, h1f, h1b, (u16*)nullptr,
        obs, We, be, (t+1 < cache_start) ? embb : (u16*)nullptr, t+1);
    gemm_dual_kernel<<<dual_grid, blk, 0, stream>>>(
        h1b, NH, NH, wE2i, e2bih, gx,
        h2b, NH, NH, wE2h, e2bhh, gh);
    if (t == NT - 2)
      gru_cell_out_kernel<<<cell_grid, blk, 0, stream>>>(
          gx, gh, h2f, h2f, h2b, Wout, bout, (float*)nullptr, 0, Wed, bed, dembb);
    else
      gru_cell_kernel<<<cell_grid, blk, 0, stream>>>(gx, gh, h2f, h2f, h2b, (u16*)nullptr);
  }
  for (int t = cache_start; t < NT; ++t){
    const u16* enc1_t = cache + (size_t)(t - cache_start)*NB*NH;
    gemm_dual_kernel<<<dual_grid, blk, 0, stream>>>(
        enc1_t, NH, NH, wE2i, e2bih, gx,
        h2b,    NH, NH, wE2h, e2bhh, gh);
    if (t == NT - 2)
      gru_cell_out_kernel<<<cell_grid, blk, 0, stream>>>(
          gx, gh, h2f, h2f, h2b, Wout, bout, (float*)nullptr, 0, Wed, bed, dembb);
    else
      gru_cell_kernel<<<cell_grid, blk, 0, stream>>>(gx, gh, h2f, h2f, h2b, (u16*)nullptr);
  }

  // ---- autoregressive decoder (carry = h2, intermediate = h1) ----
  for (int t = 0; t < NPRED; ++t){
    gemm_dual_kernel<<<dual_grid, blk, 0, stream>>>(
        dembb, NE, NE, wD1i, d1bih, gx,
        h2b,   NH, NH, wD1h, d1bhh, gh);
    gru_cell_kernel<<<cell_grid, blk, 0, stream>>>(gx, gh, h2f, h1f, h1b, (u16*)nullptr);
    gemm_dual_kernel<<<dual_grid, blk, 0, stream>>>(
        h1b, NH, NH, wD2i, d2bih, gx,
        h1b, NH, NH, wD2h, d2bhh, gh);
    gru_cell_out_kernel<<<cell_grid, blk, 0, stream>>>(
        gx, gh, h1f, h2f, h2b, Wout, bout, out, t, Wed, bed, dembb);
  }
}